// Round 4
// baseline (356.592 us; speedup 1.0000x reference)
//
#include <hip/hip_runtime.h>

#define SEQ    512
#define BATCHN 32768
#define NC     16      // chunks
#define CL     32      // steps per chunk (NC*CL == SEQ)
#define SMINF  0.01f
#define SMAXF  36500.0f

struct Params {
    float civ0, civ1;          // clip(w0), clip(w1)
    float d0, d1, d2, d3;      // ef delta per rating r: w5 - w3*((r+1)-w4)^2
};

__device__ __forceinline__ Params make_params(const float* __restrict__ wp) {
    Params p;
    const float w0 = wp[0], w1 = wp[1], w3 = wp[3], w4 = wp[4], w5 = wp[5];
    p.civ0 = fminf(fmaxf(w0, SMINF), SMAXF);
    p.civ1 = fminf(fmaxf(w1, SMINF), SMAXF);
    const float e0 = 1.0f - w4, e1 = 2.0f - w4, e2 = 3.0f - w4, e3 = 4.0f - w4;
    p.d0 = w5 - w3 * (e0 * e0);
    p.d1 = w5 - w3 * (e1 * e1);
    p.d2 = w5 - w3 * (e2 * e2);
    p.d3 = w5 - w3 * (e3 * e3);
    return p;
}

// One SM-2 step; identical in passes B and C so states agree bit-exactly.
__device__ __forceinline__ void sm2_step(unsigned r, float& ivl, float& ef, float& reps,
                                         const Params& p) {
    const bool succ = r > 1u;
    reps = succ ? (reps + 1.0f) : 1.0f;
    const float prod = fminf(fmaxf(ivl * ef, SMINF), SMAXF);     // uses OLD ef
    ivl = (reps == 1.0f) ? p.civ0 : ((reps == 2.0f) ? p.civ1 : prod);
    const float da = (r & 1u) ? p.d1 : p.d0;
    const float db = (r & 1u) ? p.d3 : p.d2;
    const float dl = (r & 2u) ? db : da;
    ef = fminf(fmaxf(ef + dl, 1.3f), 10.0f);
}

// ---------------------------------------------------------------------------
// Pass A: compress ratings to 2 bits. 2 chains/thread via float4 loads
// (16 B/lane, 1 KB/wave per instruction); ulonglong2 packed store.
// ---------------------------------------------------------------------------
__global__ __launch_bounds__(256) void k_compress(const float4* __restrict__ in4,
                                                  unsigned long long* __restrict__ rat) {
    const int tid = blockIdx.x * 256 + threadIdx.x;   // [0, NC*BATCHN/2)
    const int c = tid >> 14;                          // chunk
    const int g = tid & 16383;                        // 2-chain group
    const float4* p = in4 + (size_t)(c * CL) * (BATCHN / 2) + g;
    unsigned lo0 = 0u, hi0 = 0u, lo1 = 0u, hi1 = 0u;
#pragma unroll
    for (int t = 0; t < CL; ++t) {
        const float4 v = p[(size_t)t * (BATCHN / 2)];
        const unsigned u0 = (unsigned)v.y;            // rating, chain b0
        const unsigned u1 = (unsigned)v.w;            // rating, chain b0+1
        if (t < 16) { lo0 |= u0 << (2 * t);        lo1 |= u1 << (2 * t); }
        else        { hi0 |= u0 << (2 * (t - 16)); hi1 |= u1 << (2 * (t - 16)); }
    }
    ulonglong2 wv;
    wv.x = ((unsigned long long)hi0 << 32) | lo0;
    wv.y = ((unsigned long long)hi1 << 32) | lo1;
    ((ulonglong2*)rat)[c * (BATCHN / 2) + g] = wv;    // 16B-aligned store
}

// ---------------------------------------------------------------------------
// Pass B: full serial (ivl,ef,reps) scan per chain over packed ratings
// (128 B/thread). Emits packed float4 state at each chunk start and writes
// final_state directly.
// ---------------------------------------------------------------------------
__global__ __launch_bounds__(256) void k_scan(const unsigned long long* __restrict__ rat,
                                              const float* __restrict__ wp,
                                              float4* __restrict__ stS,
                                              float* __restrict__ out) {
    const int b = blockIdx.x * 256 + threadIdx.x;
    const Params p = make_params(wp);
    float ivl = 0.0f, ef = wp[2], reps = 0.0f;
    unsigned long long wcur = rat[b];
#pragma unroll 1
    for (int c = 0; c < NC; ++c) {
        unsigned long long wnext = 0ull;
        if (c + 1 < NC) wnext = rat[(c + 1) * BATCHN + b];   // prefetch next chunk
        float4 st; st.x = ivl; st.y = ef; st.z = reps; st.w = 0.0f;
        stS[c * BATCHN + b] = st;
        const unsigned lo = (unsigned)wcur, hi = (unsigned)(wcur >> 32);
#pragma unroll
        for (int t = 0; t < CL; ++t) {
            const unsigned r = ((t < 16 ? lo : hi) >> ((2 * t) & 31)) & 3u;
            sm2_step(r, ivl, ef, reps, p);
        }
        wcur = wnext;
    }
    float* f = out + (size_t)SEQ * BATCHN * 3 + (size_t)b * 3;
    f[0] = ivl; f[1] = ef; f[2] = reps;
}

// ---------------------------------------------------------------------------
// Pass C: concrete replay, 4 chains/thread. Per step each thread writes
// 48 B as 3 float4 stores (16B-aligned); a wave covers 3 KB contiguous.
// ---------------------------------------------------------------------------
__global__ __launch_bounds__(256) void k_emit(const unsigned long long* __restrict__ rat,
                                              const float* __restrict__ wp,
                                              const float4* __restrict__ stS,
                                              float* __restrict__ out) {
    const int tid = blockIdx.x * 256 + threadIdx.x;   // [0, NC*BATCHN/4)
    const int c = tid >> 13;                          // chunk
    const int g = tid & 8191;                         // 4-chain group
    const int b0 = g << 2;
    const Params p = make_params(wp);

    float ivl[4], ef[4], reps[4];
    unsigned lo[4], hi[4];
#pragma unroll
    for (int j = 0; j < 4; ++j) {
        const float4 st = stS[c * BATCHN + b0 + j];
        ivl[j] = st.x; ef[j] = st.y; reps[j] = st.z;
        const unsigned long long w = rat[c * BATCHN + b0 + j];
        lo[j] = (unsigned)w; hi[j] = (unsigned)(w >> 32);
    }

    // out float4 index: ((c*CL)*BATCHN + b0)*3/4 = (c*CL)*(BATCHN*3/4) + 3*g
    float4* ob = (float4*)out + (size_t)(c * CL) * (BATCHN * 3 / 4) + (size_t)3 * g;
#pragma unroll
    for (int t = 0; t < CL; ++t) {
#pragma unroll
        for (int j = 0; j < 4; ++j) {
            const unsigned r = ((t < 16 ? lo[j] : hi[j]) >> ((2 * t) & 31)) & 3u;
            sm2_step(r, ivl[j], ef[j], reps[j], p);
        }
        float4 va, vb, vc;
        va.x = ivl[0]; va.y = ef[0];  va.z = reps[0]; va.w = ivl[1];
        vb.x = ef[1];  vb.y = reps[1]; vb.z = ivl[2]; vb.w = ef[2];
        vc.x = reps[2]; vc.y = ivl[3]; vc.z = ef[3];  vc.w = reps[3];
        ob[0] = va; ob[1] = vb; ob[2] = vc;
        ob += (size_t)(BATCHN * 3 / 4);
    }
}

extern "C" void kernel_launch(void* const* d_in, const int* in_sizes, int n_in,
                              void* d_out, int out_size, void* d_ws, size_t ws_size,
                              hipStream_t stream) {
    const float4* in4 = (const float4*)d_in[0];
    const float* w    = (const float*)d_in[1];
    float* out        = (float*)d_out;
    char* ws          = (char*)d_ws;

    // ws layout (12.6 MB): rat 4 MB, stS 8 MB
    unsigned long long* rat = (unsigned long long*)(ws);        // 16*32768*8  = 4,194,304 B
    float4* stS             = (float4*)(ws + 4194304);          // 16*32768*16 = 8,388,608 B

    k_compress<<<NC * BATCHN / 2 / 256, 256, 0, stream>>>(in4, rat);
    k_scan    <<<BATCHN / 256,          256, 0, stream>>>(rat, w, stS, out);
    k_emit    <<<NC * BATCHN / 4 / 256, 256, 0, stream>>>(rat, w, stS, out);
}

// Round 6
// 355.923 us; speedup vs baseline: 1.0019x; 1.0019x over previous
//
#include <hip/hip_runtime.h>

#define SEQ    512
#define BATCHN 32768
#define CHB    64            // chains per block (== wavefront size)
#define NSEG   4             // time segments == waves per block
#define SEGL   (SEQ / NSEG)  // 128 steps per segment
#define SMINF  0.01f
#define SMAXF  36500.0f

struct Params {
    float civ0, civ1;        // clip(w0), clip(w1)
    float d0, d1, d2, d3;    // ef delta per rating r: w5 - w3*((r+1)-w4)^2
};

__device__ __forceinline__ Params make_params(const float* __restrict__ wp) {
    Params p;
    const float w0 = wp[0], w1 = wp[1], w3 = wp[3], w4 = wp[4], w5 = wp[5];
    p.civ0 = fminf(fmaxf(w0, SMINF), SMAXF);
    p.civ1 = fminf(fmaxf(w1, SMINF), SMAXF);
    const float e0 = 1.0f - w4, e1 = 2.0f - w4, e2 = 3.0f - w4, e3 = 4.0f - w4;
    p.d0 = w5 - w3 * (e0 * e0);
    p.d1 = w5 - w3 * (e1 * e1);
    p.d2 = w5 - w3 * (e2 * e2);
    p.d3 = w5 - w3 * (e3 * e3);
    return p;
}

__device__ __forceinline__ void sm2_step(unsigned r, float& ivl, float& ef, float& reps,
                                         const Params& p) {
    const bool succ = r > 1u;
    reps = succ ? (reps + 1.0f) : 1.0f;
    const float prod = fminf(fmaxf(ivl * ef, SMINF), SMAXF);     // uses OLD ef
    ivl = (reps == 1.0f) ? p.civ0 : ((reps == 2.0f) ? p.civ1 : prod);
    const float da = (r & 1u) ? p.d1 : p.d0;
    const float db = (r & 1u) ? p.d3 : p.d2;
    const float dl = (r & 2u) ? db : da;
    ef = fminf(fmaxf(ef + dl, 1.3f), 10.0f);
}

// ---------------------------------------------------------------------------
// Single fused kernel. Block = 4 waves x 64 lanes; lane = chain, wave = time
// segment. Phase 1 packs the block's 64-chain rating column into LDS bit
// planes (2 ballots per t-slice). Phase 2: wave s re-derives the state at
// t=128*s from the planes (redundant VALU, overlapped), then emits its
// 128-step segment with contiguous 768 B/wave stores.
// ---------------------------------------------------------------------------
__global__ __launch_bounds__(256) void k_fused(const float2* __restrict__ in2,
                                               const float* __restrict__ wp,
                                               float* __restrict__ out) {
    __shared__ ulonglong2 pk[SEQ];         // bit planes: x = bit0, y = bit1 (8 KB)
    const int l  = threadIdx.x & 63;       // chain lane
    const int s  = threadIdx.x >> 6;       // wave = segment
    const int B0 = blockIdx.x * CHB;

    // ---- Phase 1: load + ballot-pack ratings -----------------------------
#pragma unroll 8
    for (int t = s; t < SEQ; t += NSEG) {
        const float2 v = in2[(size_t)t * BATCHN + B0 + l];   // 512 B/wave, coalesced
        const unsigned r = (unsigned)v.y;
        const unsigned long long m0 = __ballot(r & 1u);
        const unsigned long long m1 = __ballot(r & 2u);
        if (l == 0) {
            ulonglong2 m; m.x = m0; m.y = m1;
            pk[t] = m;                                        // ds_write_b128
        }
    }
    __syncthreads();

    // ---- Phase 2: prefix re-derivation + emit ----------------------------
    const Params p = make_params(wp);
    float ivl = 0.0f, ef = wp[2], reps = 0.0f;

    const int t0 = s * SEGL;
#pragma unroll 4
    for (int t = 0; t < t0; ++t) {                            // redundant prefix (VALU only)
        const ulonglong2 m = pk[t];                           // broadcast ds_read_b128
        const unsigned r = ((unsigned)(m.x >> l) & 1u) | (((unsigned)(m.y >> l) & 1u) << 1);
        sm2_step(r, ivl, ef, reps, p);
    }

    float* ob = out + ((size_t)t0 * BATCHN + B0 + l) * 3;
#pragma unroll 4
    for (int k = 0; k < SEGL; ++k) {                          // emit segment
        const ulonglong2 m = pk[t0 + k];
        const unsigned r = ((unsigned)(m.x >> l) & 1u) | (((unsigned)(m.y >> l) & 1u) << 1);
        sm2_step(r, ivl, ef, reps, p);
        ob[0] = ivl; ob[1] = ef; ob[2] = reps;                // 12 B/lane, 768 B/wave
        ob += (size_t)BATCHN * 3;
    }

    if (s == NSEG - 1) {                                      // final_state
        float* f = out + (size_t)SEQ * BATCHN * 3 + (size_t)(B0 + l) * 3;
        f[0] = ivl; f[1] = ef; f[2] = reps;
    }
}

extern "C" void kernel_launch(void* const* d_in, const int* in_sizes, int n_in,
                              void* d_out, int out_size, void* d_ws, size_t ws_size,
                              hipStream_t stream) {
    const float2* in2 = (const float2*)d_in[0];
    const float* w    = (const float*)d_in[1];
    float* out        = (float*)d_out;

    k_fused<<<BATCHN / CHB, 256, 0, stream>>>(in2, w, out);   // 512 blocks, 2/CU
}

// Round 7
// 324.448 us; speedup vs baseline: 1.0991x; 1.0970x over previous
//
#include <hip/hip_runtime.h>

#define SEQ    512
#define BATCHN 32768
#define NTHR   (BATCHN / 2)   // 16384 threads, 2 chains per thread
#define PF     16             // prefetch depth (float4 iterations in registers)
#define SMINF  0.01f
#define SMAXF  36500.0f

typedef __attribute__((ext_vector_type(2))) float f32x2;

struct Params {
    float civ0, civ1;          // clip(w0), clip(w1)
    float d0, d1, d2, d3;      // ef delta per rating r: w5 - w3*((r+1)-w4)^2
};

__device__ __forceinline__ Params make_params(const float* __restrict__ wp) {
    Params p;
    const float w0 = wp[0], w1 = wp[1], w3 = wp[3], w4 = wp[4], w5 = wp[5];
    p.civ0 = fminf(fmaxf(w0, SMINF), SMAXF);
    p.civ1 = fminf(fmaxf(w1, SMINF), SMAXF);
    const float e0 = 1.0f - w4, e1 = 2.0f - w4, e2 = 3.0f - w4, e3 = 4.0f - w4;
    p.d0 = w5 - w3 * (e0 * e0);
    p.d1 = w5 - w3 * (e1 * e1);
    p.d2 = w5 - w3 * (e2 * e2);
    p.d3 = w5 - w3 * (e3 * e3);
    return p;
}

__device__ __forceinline__ void sm2_step(unsigned r, float& ivl, float& ef, float& reps,
                                         const Params& p) {
    const bool succ = r > 1u;
    reps = succ ? (reps + 1.0f) : 1.0f;
    const float prod = fminf(fmaxf(ivl * ef, SMINF), SMAXF);     // uses OLD ef
    ivl = (reps == 1.0f) ? p.civ0 : ((reps == 2.0f) ? p.civ1 : prod);
    const float da = (r & 1u) ? p.d1 : p.d0;
    const float db = (r & 1u) ? p.d3 : p.d2;
    const float dl = (r & 2u) ? db : da;
    ef = fminf(fmaxf(ef + dl, 1.3f), 10.0f);
}

// ---------------------------------------------------------------------------
// Single streaming kernel, R1 skeleton upgraded. One thread owns 2 adjacent
// chains: float4 input loads (16 B/lane, 1 KB/wave), 24 B/lane output per
// step as 3 nontemporal f32x2 stores (1.5 KB/wave contiguous). Explicit
// buf/nxt register arrays force PF=16 loads in flight (the round-6 profile
// showed the compiler otherwise allocates 12 VGPRs and serializes on memory
// latency). 256 blocks x 1 wave = exactly 1 block per CU.
// ---------------------------------------------------------------------------
__global__ __launch_bounds__(64) void k_stream(const float4* __restrict__ in4,
                                               const float* __restrict__ wp,
                                               float* __restrict__ out) {
    const int tid = blockIdx.x * 64 + threadIdx.x;   // [0, NTHR)
    const Params p = make_params(wp);

    float i0 = 0.0f, e0 = wp[2], r0 = 0.0f;          // chain 2*tid
    float i1 = 0.0f, e1 = wp[2], r1 = 0.0f;          // chain 2*tid+1

    const float4* __restrict__ ip = in4 + tid;       // stride NTHR float4 per t
    f32x2* const ob = (f32x2*)(out + (size_t)tid * 6);
    const size_t ostr = (size_t)BATCHN * 3 / 2;      // f32x2 per t-slice

    float4 buf[PF];
#pragma unroll
    for (int i = 0; i < PF; ++i) buf[i] = ip[(size_t)i * NTHR];

    for (int t0 = 0; t0 < SEQ; t0 += PF) {
        float4 nxt[PF];
        const bool more = (t0 + PF) < SEQ;
        if (more) {
#pragma unroll
            for (int i = 0; i < PF; ++i)
                nxt[i] = ip[(size_t)(t0 + PF + i) * NTHR];
        }

#pragma unroll
        for (int i = 0; i < PF; ++i) {
            const unsigned ra = (unsigned)buf[i].y;  // rating, chain 2*tid
            const unsigned rb = (unsigned)buf[i].w;  // rating, chain 2*tid+1
            sm2_step(ra, i0, e0, r0, p);
            sm2_step(rb, i1, e1, r1, p);

            f32x2* o = ob + (size_t)(t0 + i) * ostr;
            f32x2 va; va.x = i0; va.y = e0;
            f32x2 vb; vb.x = r0; vb.y = i1;
            f32x2 vc; vc.x = e1; vc.y = r1;
            __builtin_nontemporal_store(va, o + 0);
            __builtin_nontemporal_store(vb, o + 1);
            __builtin_nontemporal_store(vc, o + 2);
        }

        if (more) {
#pragma unroll
            for (int i = 0; i < PF; ++i) buf[i] = nxt[i];
        }
    }

    // final_state (32768, 3) appended after outputs
    float* f = out + (size_t)SEQ * BATCHN * 3 + (size_t)tid * 6;
    f[0] = i0; f[1] = e0; f[2] = r0;
    f[3] = i1; f[4] = e1; f[5] = r1;
}

extern "C" void kernel_launch(void* const* d_in, const int* in_sizes, int n_in,
                              void* d_out, int out_size, void* d_ws, size_t ws_size,
                              hipStream_t stream) {
    const float4* in4 = (const float4*)d_in[0];
    const float* w    = (const float*)d_in[1];
    float* out        = (float*)d_out;

    k_stream<<<NTHR / 64, 64, 0, stream>>>(in4, w, out);   // 256 blocks, 1 wave each
}